// Round 2
// baseline (150.857 us; speedup 1.0000x reference)
//
#include <hip/hip_runtime.h>

#define IN_F 1024
#define OUT_F 1024
#define NTOK 32768
#define BM 128
#define BN 128
#define BK 64
#define KT (IN_F / BK)  // 16 K-tiles

typedef __bf16 bf16;
typedef __bf16 bf16x4 __attribute__((ext_vector_type(4)));
typedef __bf16 bf16x8 __attribute__((ext_vector_type(8)));
typedef float f32x4 __attribute__((ext_vector_type(4)));

// ---------------------------------------------------------------------------
// Kernel 1: build patched bf16 weight W' (unchanged from round 1; correct).
// ---------------------------------------------------------------------------
__global__ void build_wp(const float* __restrict__ W,
                         const int* __restrict__ rows,
                         const int* __restrict__ srcs,
                         const int* __restrict__ clones,
                         bf16* __restrict__ Wp) {
  const int r = blockIdx.x;
  const int row = rows[r];
  const int s = srcs[r];
  const int c0 = clones[3 * r + 0];
  const int c1 = clones[3 * r + 1];
  const int c2 = clones[3 * r + 2];
  const float* wr = W + (size_t)row * IN_F;
  const float fixv = 0.25f * (wr[s] + wr[c0] + wr[c1] + wr[c2]);

  const int col = threadIdx.x * 4;
  f32x4 v = *reinterpret_cast<const f32x4*>(wr + col);
  bf16x4 o;
#pragma unroll
  for (int j = 0; j < 4; ++j) {
    const int c = col + j;
    float f = v[j];
    if (c == c0 || c == c1 || c == c2) f = 0.0f;
    if (c == s) f = fixv;
    o[j] = (bf16)f;
  }
  *reinterpret_cast<bf16x4*>(Wp + (size_t)row * IN_F + col) = o;
}

// ---------------------------------------------------------------------------
// Kernel 2: out = X @ W'^T + bias.  128x128 tile, BK=64, 4 waves (2x2),
// double-buffered LDS, counted-vmcnt pipeline (T3+T4), XOR-swizzled LDS (T2).
//
// LDS layout (both A and B): [row][64 bf16] = 128B rows; 16B slot s of row r
// stored at physical slot s ^ (r&7)  -> conflict-free ds_read_b128.
// A: fp32 global -> regs (prefetch dist 2) -> cvt -> swizzled ds_write.
// B: global_load_lds (linear dest) with pre-swizzled global source (rule 21).
// Per K-tile per thread: 8 A-loads (dwordx4) + 4 B gload_lds.
// Tail wait: vmcnt(8) leaves next A-loads in flight, drains B. One barrier/tile.
// ---------------------------------------------------------------------------
__global__ __launch_bounds__(256, 2) void gemm_rewire(
    const float* __restrict__ X, const bf16* __restrict__ Wp,
    const float* __restrict__ bias, float* __restrict__ out) {
  __shared__ __align__(16) bf16 lA[2][BM * BK];  // 16KB each
  __shared__ __align__(16) bf16 lB[2][BN * BK];  // 16KB each

  const int tid = threadIdx.x;
  const int lane = tid & 63;
  const int w = tid >> 6;   // wave 0..3
  const int wr = w >> 1;    // wave row (64 out-rows)
  const int wc = w & 1;     // wave col (64 out-cols)
  const int bm = blockIdx.x;
  const int bn = blockIdx.y;

  // --- A global staging: load j covers row j*16 + tid/16, 16B at col (tid&15)*4
  const float* gA =
      X + ((size_t)bm * BM + (tid >> 4)) * IN_F + (tid & 15) * 4;
  // --- A LDS write (swizzled): row_j = j*16 + (tid>>4)
  const int arx7 = (tid >> 4) & 7;
  const int awbyte0 =
      (tid >> 4) * 128 + (((((tid & 15) >> 1)) ^ arx7) * 16) + (tid & 1) * 8;
  // j adds 16*128 = 2048 bytes

  // --- B staging (pre-swizzled global source; linear gldsB dest):
  // issue i: LDS bytes i*4096 + w*1024 + lane*16 -> row i*32+w*8+(lane>>3),
  // phys slot lane&7; logical slot = (lane&7) ^ (lane>>3).
  const bf16* gB = Wp + ((size_t)bn * BN + w * 8 + (lane >> 3)) * IN_F +
                   (((lane & 7) ^ (lane >> 3)) * 8);

  // --- accumulators preloaded with bias
  f32x4 acc[4][4];
#pragma unroll
  for (int n = 0; n < 4; ++n) {
    const float bv = bias[bn * BN + wc * 64 + n * 16 + (lane & 15)];
#pragma unroll
    for (int m = 0; m < 4; ++m) acc[m][n] = (f32x4){bv, bv, bv, bv};
  }

  // --- fragment read geometry
  const int arow = wr * 64 + (lane & 15);
  const int brow = wc * 64 + (lane & 15);
  const int slot0 = lane >> 4;
  const int ax7 = arow & 7;  // == (lane&15)&7
  const int bx7 = brow & 7;

  f32x4 av[8];

  auto issueA = [&](int kt2) {
#pragma unroll
    for (int j = 0; j < 8; ++j)
      av[j] = *reinterpret_cast<const f32x4*>(gA + (size_t)j * 16 * IN_F +
                                              (size_t)kt2 * BK);
  };
  auto writeA = [&](int buf) {
    char* base = (char*)lA[buf];
#pragma unroll
    for (int j = 0; j < 8; ++j) {
      bf16x4 o;
      o[0] = (bf16)av[j][0];
      o[1] = (bf16)av[j][1];
      o[2] = (bf16)av[j][2];
      o[3] = (bf16)av[j][3];
      *reinterpret_cast<bf16x4*>(base + j * 2048 + awbyte0) = o;
    }
  };
  auto issueB = [&](int kt2, int buf) {
    const bf16* g = gB + (size_t)kt2 * BK;
#pragma unroll
    for (int i = 0; i < 4; ++i) {
      char* dst = (char*)lB[buf] + i * 4096 + w * 1024;  // wave-uniform base
      __builtin_amdgcn_global_load_lds(
          (const __attribute__((address_space(1))) void*)(g +
                                                          (size_t)i * 32 * IN_F),
          (__attribute__((address_space(3))) void*)dst, 16, 0, 0);
    }
  };
  auto compute = [&](int buf) {
    const char* A = (const char*)lA[buf];
    const char* B = (const char*)lB[buf];
#pragma unroll
    for (int kk = 0; kk < 2; ++kk) {
      const int sa = ((slot0 + kk * 4) ^ ax7) * 16;
      const int sb = ((slot0 + kk * 4) ^ bx7) * 16;
      bf16x8 af[4], bfr[4];
#pragma unroll
      for (int m = 0; m < 4; ++m)
        af[m] = *reinterpret_cast<const bf16x8*>(A + (arow + m * 16) * 128 + sa);
#pragma unroll
      for (int n = 0; n < 4; ++n)
        bfr[n] =
            *reinterpret_cast<const bf16x8*>(B + (brow + n * 16) * 128 + sb);
#pragma unroll
      for (int m = 0; m < 4; ++m)
#pragma unroll
        for (int n = 0; n < 4; ++n)
          acc[m][n] = __builtin_amdgcn_mfma_f32_16x16x32_bf16(
              af[m], bfr[n], acc[m][n], 0, 0, 0);
    }
  };

  // --- prologue
  issueA(0);
  issueB(0, 0);
  __builtin_amdgcn_sched_barrier(0);
  writeA(0);      // compiler waits A(0) vmem
  issueA(1);
  asm volatile("s_waitcnt vmcnt(8) lgkmcnt(0)" ::: "memory");  // drain B(0)
  __builtin_amdgcn_s_barrier();
  issueB(1, 1);
  __builtin_amdgcn_sched_barrier(0);

  int cur = 0;
  for (int t = 0; t < KT; ++t) {
    if (t + 1 < KT) writeA(cur ^ 1);  // A(t+1) regs -> lA[cur^1] (swizzled)
    if (t + 2 < KT) issueA(t + 2);    // queued AFTER B(t+1)
    compute(cur);
    if (t + 1 < KT) {
      if (t + 2 < KT)
        asm volatile("s_waitcnt vmcnt(8) lgkmcnt(0)" ::: "memory");  // drain B(t+1), keep A(t+2)
      else
        asm volatile("s_waitcnt vmcnt(0) lgkmcnt(0)" ::: "memory");
      __builtin_amdgcn_s_barrier();
      if (t + 2 < KT) {
        issueB(t + 2, cur);  // overwrite just-consumed B buffer
        __builtin_amdgcn_sched_barrier(0);
      }
      cur ^= 1;
    }
  }

  // --- epilogue: C/D layout col = lane&15, row = (lane>>4)*4 + i
  const int orow0 = bm * BM + wr * 64 + (lane >> 4) * 4;
  const int ocol0 = bn * BN + wc * 64 + (lane & 15);
#pragma unroll
  for (int m = 0; m < 4; ++m) {
#pragma unroll
    for (int n = 0; n < 4; ++n) {
      const f32x4 v = acc[m][n];
      const size_t base = (size_t)(orow0 + m * 16) * OUT_F + (ocol0 + n * 16);
#pragma unroll
      for (int i = 0; i < 4; ++i) out[base + (size_t)i * OUT_F] = v[i];
    }
  }
}

// ---------------------------------------------------------------------------
extern "C" void kernel_launch(void* const* d_in, const int* in_sizes, int n_in,
                              void* d_out, int out_size, void* d_ws,
                              size_t ws_size, hipStream_t stream) {
  const float* x = (const float*)d_in[0];
  const float* weight = (const float*)d_in[1];
  const float* bias = (const float*)d_in[2];
  const int* rrows = (const int*)d_in[3];
  const int* rsrc = (const int*)d_in[4];
  const int* rclones = (const int*)d_in[5];
  float* out = (float*)d_out;
  bf16* Wp = (bf16*)d_ws;  // 2 MB scratch

  build_wp<<<dim3(OUT_F), dim3(256), 0, stream>>>(weight, rrows, rsrc, rclones,
                                                  Wp);
  gemm_rewire<<<dim3(NTOK / BM, OUT_F / BN), dim3(256), 0, stream>>>(x, Wp,
                                                                     bias, out);
}

// Round 4
// 106.281 us; speedup vs baseline: 1.4194x; 1.4194x over previous
//
#include <hip/hip_runtime.h>

#define IN_F 1024
#define OUT_F 1024
#define NTOK 32768
#define BM 256
#define BN 256
#define BK 64
#define KT (IN_F / BK)  // 16 K-tiles

typedef __bf16 bf16;
typedef __bf16 bf16x4 __attribute__((ext_vector_type(4)));
typedef __bf16 bf16x8 __attribute__((ext_vector_type(8)));
typedef float f32x4 __attribute__((ext_vector_type(4)));

// ---------------------------------------------------------------------------
// Kernel 1: build patched bf16 weight W' (validated rounds 1-2).
// ---------------------------------------------------------------------------
__global__ void build_wp(const float* __restrict__ W,
                         const int* __restrict__ rows,
                         const int* __restrict__ srcs,
                         const int* __restrict__ clones,
                         bf16* __restrict__ Wp) {
  const int r = blockIdx.x;
  const int row = rows[r];
  const int s = srcs[r];
  const int c0 = clones[3 * r + 0];
  const int c1 = clones[3 * r + 1];
  const int c2 = clones[3 * r + 2];
  const float* wr = W + (size_t)row * IN_F;
  const float fixv = 0.25f * (wr[s] + wr[c0] + wr[c1] + wr[c2]);

  const int col = threadIdx.x * 4;
  f32x4 v = *reinterpret_cast<const f32x4*>(wr + col);
  bf16x4 o;
#pragma unroll
  for (int j = 0; j < 4; ++j) {
    const int c = col + j;
    float f = v[j];
    if (c == c0 || c == c1 || c == c2) f = 0.0f;
    if (c == s) f = fixv;
    o[j] = (bf16)f;
  }
  *reinterpret_cast<bf16x4*>(Wp + (size_t)row * IN_F + col) = o;
}

// ---------------------------------------------------------------------------
// Kernel 2: out = X @ W'^T + bias.
// 256x256 tile, 8 waves (2Mx4N, per-wave 128x64), BK=64, double-buffered
// 128KB dynamic LDS, ONE barrier per K-tile. 128B LDS rows with the
// round-2-validated XOR swizzle (slot_phys = slot ^ (row&7)), zero conflicts.
// A (fp32): global->reg (issued at tile start) -> cvt -> swizzled ds_write
//           (after compute; compiler emits vmcnt(4), leaving B in flight).
// B (bf16): global_load_lds, linear dest + pre-swizzled global source.
// ---------------------------------------------------------------------------
__global__ __launch_bounds__(512, 2) void gemm_rewire(
    const float* __restrict__ X, const bf16* __restrict__ Wp,
    const float* __restrict__ bias, float* __restrict__ out) {
  extern __shared__ __align__(16) char smem[];  // 128KB: A0 A1 B0 B1 (32KB ea)

  const int tid = threadIdx.x;
  const int lane = tid & 63;
  const int w = tid >> 6;    // 0..7
  const int wrow = w >> 2;   // 0..1  (128-row half of A)
  const int wcol = w & 3;    // 0..3  (64-col quarter of B)

  // XCD-grouped decode: the 4 bn-sharers of an X-panel run consecutively on
  // the SAME XCD (bid&7 = XCD slot by round-robin dispatch).
  const int bid = blockIdx.x;                // 0..511
  const int sq = bid >> 3;                   // 0..63 per-XCD sequence
  const int bm = (bid & 7) + 8 * (sq >> 2);  // 0..127
  const int bn = sq & 3;                     // 0..3

  // --- A staging: thread owns rows (tid>>3)+j*64, fp32 cols (tid&7)*8..+8
  const float* gA = X + ((size_t)bm * BM + (tid >> 3)) * IN_F + (tid & 7) * 8;
  // ds_write byte offset (row-part + swizzled 16B slot), j adds 64*128 bytes
  const int awbyte =
      ((tid >> 3) << 7) + ((((tid & 7) ^ ((tid >> 3) & 7))) << 4);

  // --- B staging: linear gload_lds dest; pre-swizzled global source.
  // issue i: LDS row = i*64 + w*8 + (lane>>3), phys slot lane&7
  const bf16* gB = Wp + ((size_t)bn * BN + w * 8 + (lane >> 3)) * IN_F +
                   (((lane & 7) ^ ((lane >> 3) & 7)) << 3);

  // --- accumulators preloaded with bias (C/D col = lane&15)
  f32x4 acc[8][4];
#pragma unroll
  for (int n = 0; n < 4; ++n) {
    const float bv = bias[bn * BN + wcol * 64 + n * 16 + (lane & 15)];
#pragma unroll
    for (int m = 0; m < 8; ++m) acc[m][n] = (f32x4){bv, bv, bv, bv};
  }

  // --- fragment geometry
  const int arow0 = wrow * 128 + (lane & 15);  // + m*16
  const int brow0 = wcol * 64 + (lane & 15);   // + n*16
  const int sl0 = lane >> 4;                   // logical slot, + kk*4
  const int lx7 = lane & 7;                    // == row&7 for all frag rows

  f32x4 av[8];

  auto issueA = [&](int t) {
#pragma unroll
    for (int j = 0; j < 4; ++j) {
      const float* p = gA + (size_t)j * 64 * IN_F + (size_t)t * BK;
      av[2 * j] = *reinterpret_cast<const f32x4*>(p);
      av[2 * j + 1] = *reinterpret_cast<const f32x4*>(p + 4);
    }
  };
  auto writeA = [&](int buf) {
    char* base = smem + buf * 32768;
#pragma unroll
    for (int j = 0; j < 4; ++j) {
      bf16x8 o;
#pragma unroll
      for (int q = 0; q < 4; ++q) {
        o[q] = (bf16)av[2 * j][q];
        o[4 + q] = (bf16)av[2 * j + 1][q];
      }
      *reinterpret_cast<bf16x8*>(base + j * 8192 + awbyte) = o;
    }
  };
  auto issueB = [&](int t, int buf) {
    const bf16* g = gB + (size_t)t * BK;
    char* dst0 = smem + 65536 + buf * 32768 + w * 1024;  // wave-uniform base
#pragma unroll
    for (int i = 0; i < 4; ++i) {
      __builtin_amdgcn_global_load_lds(
          (const __attribute__((address_space(1))) void*)(g +
                                                          (size_t)i * 64 * IN_F),
          (__attribute__((address_space(3))) void*)(dst0 + i * 8192), 16, 0, 0);
    }
  };
  auto compute = [&](int buf) {
    const char* A = smem + buf * 32768;
    const char* B = smem + 65536 + buf * 32768;
#pragma unroll
    for (int kk = 0; kk < 2; ++kk) {
      const int sl = sl0 + kk * 4;
      const int so = ((sl ^ lx7) << 4);
      bf16x8 af[8], bfr[4];
#pragma unroll
      for (int m = 0; m < 8; ++m)
        af[m] =
            *reinterpret_cast<const bf16x8*>(A + (arow0 + m * 16) * 128 + so);
#pragma unroll
      for (int n = 0; n < 4; ++n)
        bfr[n] =
            *reinterpret_cast<const bf16x8*>(B + (brow0 + n * 16) * 128 + so);
      __builtin_amdgcn_s_setprio(1);
#pragma unroll
      for (int m = 0; m < 8; ++m)
#pragma unroll
        for (int n = 0; n < 4; ++n)
          acc[m][n] = __builtin_amdgcn_mfma_f32_16x16x32_bf16(
              af[m], bfr[n], acc[m][n], 0, 0, 0);
      __builtin_amdgcn_s_setprio(0);
    }
  };

  // --- prologue: stage tile 0 into buffer 0
  issueA(0);
  issueB(0, 0);
  writeA(0);        // compiler inserts vmcnt wait for av
  __syncthreads();  // drains B(0) gloads + ds_writes

  // --- main loop: one barrier per K-tile
  for (int t = 0; t < KT; ++t) {
    const int db = t & 1;
    const bool more = (t + 1) < KT;
    if (more) {
      issueA(t + 1);          // 8 dwordx4 -> regs (in flight through compute)
      issueB(t + 1, db ^ 1);  // 4 gload_lds -> other buffer
      __builtin_amdgcn_sched_barrier(0);
    }
    compute(db);
    if (more) {
      __builtin_amdgcn_sched_barrier(0);  // keep MFMAs above the cvt/write
      writeA(db ^ 1);  // vmcnt(4): waits A, leaves B in flight
      __syncthreads();  // tile boundary (cheap: loads landed)
    }
  }

  // --- epilogue: C/D layout col = lane&15, row = (lane>>4)*4 + i
  const int orow0 = bm * BM + wrow * 128 + (lane >> 4) * 4;
  const int ocol = bn * BN + wcol * 64 + (lane & 15);
#pragma unroll
  for (int m = 0; m < 8; ++m) {
#pragma unroll
    for (int n = 0; n < 4; ++n) {
      const f32x4 v = acc[m][n];
      const size_t base = (size_t)(orow0 + m * 16) * OUT_F + (ocol + n * 16);
#pragma unroll
      for (int i = 0; i < 4; ++i) out[base + (size_t)i * OUT_F] = v[i];
    }
  }
}

// ---------------------------------------------------------------------------
extern "C" void kernel_launch(void* const* d_in, const int* in_sizes, int n_in,
                              void* d_out, int out_size, void* d_ws,
                              size_t ws_size, hipStream_t stream) {
  const float* x = (const float*)d_in[0];
  const float* weight = (const float*)d_in[1];
  const float* bias = (const float*)d_in[2];
  const int* rrows = (const int*)d_in[3];
  const int* rsrc = (const int*)d_in[4];
  const int* rclones = (const int*)d_in[5];
  float* out = (float*)d_out;
  bf16* Wp = (bf16*)d_ws;  // 2 MB scratch

  // allow 128KB dynamic LDS (host-side attribute; deterministic, capture-safe)
  (void)hipFuncSetAttribute((const void*)gemm_rewire,
                            hipFuncAttributeMaxDynamicSharedMemorySize, 131072);

  build_wp<<<dim3(OUT_F), dim3(256), 0, stream>>>(weight, rrows, rsrc, rclones,
                                                  Wp);
  gemm_rewire<<<dim3((NTOK / BM) * (OUT_F / BN)), dim3(512), 131072, stream>>>(
      x, Wp, bias, out);
}